// Round 10
// baseline (317.134 us; speedup 1.0000x reference)
//
#include <hip/hip_runtime.h>
#include <hip/hip_bf16.h>

#define N_NODES 100000
#define N_EDGES 1000000
#define S_DIM 64
#define F_DIM 64
#define RBF_DIM 16
#define V_CH 16

typedef __attribute__((ext_vector_type(4))) float f32x4;
typedef __attribute__((ext_vector_type(8))) short bf16x8;

#define NBLK 128
#define TPW 5            // tiles per wave
#define EDGE_GRID 3125   // 3125 * 4 waves * 5 tiles * 16 edges = 1,000,000 exactly

__device__ __forceinline__ float silu_f(float x) {
    return x * (1.0f / (1.0f + __expf(-x)));
}

__device__ __forceinline__ ushort f2bf(float x) {
    union { __hip_bfloat16 b; ushort u; } c;
    c.b = __float2bfloat16(x);
    return c.u;
}

__device__ __forceinline__ f32x4 ld4v(const float* p) {
    return *reinterpret_cast<const f32x4*>(p);
}

__device__ __forceinline__ bf16x8 pack8(f32x4 u, f32x4 v) {
    bf16x8 r;
    r[0] = (short)f2bf(u[0]); r[1] = (short)f2bf(u[1]);
    r[2] = (short)f2bf(u[2]); r[3] = (short)f2bf(u[3]);
    r[4] = (short)f2bf(v[0]); r[5] = (short)f2bf(v[1]);
    r[6] = (short)f2bf(v[2]); r[7] = (short)f2bf(v[3]);
    return r;
}

struct RawG { f32x4 v[8]; };   // src/dst node-scalar gathers only (cross-tile prefetch)

// ---------------- Edge kernel: swapped-operand MFMA, zero LDS round trips ----------------
// Layer 1: D1^T = W1^T(A) · x^T(B).  A-frag row=lane&15 -> h2-dim-in-block; B-frag col=lane&15 -> edge.
// Output (m89 C/D layout): lane(l15,g) holds h2[edge=l15][dim=16nn+4g+rr].
// Layer 2: W2 rows permuted by delta(kk,g,j)=16*(2kk+(j>>2))+4g+(j&3) so layer-1 output registers
// ARE the B operand -- no transpose, no LDS, no shuffles between layers.
__global__ __launch_bounds__(256, 3) void edge_kernel(
    const float* __restrict__ ns, const float* __restrict__ ef,
    const float* __restrict__ dd, const int* __restrict__ src,
    const int* __restrict__ dst, const float* __restrict__ W1,
    const float* __restrict__ b1, const float* __restrict__ W2,
    const float* __restrict__ b2, const float* __restrict__ lng,
    const float* __restrict__ lnb, float* __restrict__ out)
{
    __shared__ __align__(16) ushort b1f[7][4][64][8];   // 28672 B (write-once)
    __shared__ __align__(16) ushort b2f[2][4][64][8];   //  8192 B (write-once, row-permuted)
    // total 36864 B; no mutable LDS -> no fences needed in the loop

    const int tid  = threadIdx.x;
    const int lane = tid & 63;
    const int wid  = tid >> 6;
    const int l15  = lane & 15;
    const int g    = lane >> 4;

    // ---- one-time weight staging (sealed by syncthreads) ----
    {
        const int fl   = tid & 63;
        const int fnn  = tid >> 6;
        const int fl15 = fl & 15;
        const int fg   = fl >> 4;
        const int col  = 16 * fnn + fl15;
        const int krow = fg << 3;
        #pragma unroll
        for (int kk = 0; kk < 7; ++kk) {
            const int k0 = 32 * kk + krow;
            bf16x8 w;
            #pragma unroll
            for (int j = 0; j < 8; ++j) {
                const int k = k0 + j;
                w[j] = (k < 208) ? (short)f2bf(W1[k * 64 + col]) : (short)0;
            }
            *reinterpret_cast<bf16x8*>(&b1f[kk][fnn][fl][0]) = w;
        }
        // W2 with delta row permutation: slot (kk,fg,j) holds W2[delta][col]
        #pragma unroll
        for (int kk = 0; kk < 2; ++kk) {
            bf16x8 w;
            #pragma unroll
            for (int j = 0; j < 8; ++j) {
                const int delta = 16 * (2 * kk + (j >> 2)) + 4 * fg + (j & 3);
                w[j] = (short)f2bf(W2[delta * 64 + col]);
            }
            *reinterpret_cast<bf16x8*>(&b2f[kk][fnn][fl][0]) = w;
        }
    }
    __syncthreads();

    // per-lane bias quads: dim = 16nn + 4g + rr
    f32x4 b1q[4], b2q[4];
    #pragma unroll
    for (int nn = 0; nn < 4; ++nn) {
        b1q[nn] = ld4v(b1 + 16 * nn + 4 * g);
        b2q[nn] = ld4v(b2 + 16 * nn + 4 * g);
    }

    const int wtile0 = (blockIdx.x * 4 + wid) * TPW;

    int sis[TPW], dis[TPW];
    #pragma unroll
    for (int t = 0; t < TPW; ++t) {
        const int erow = (wtile0 + t) * 16 + l15;
        sis[t] = src[erow];
        dis[t] = dst[erow];
    }

    auto load_gather = [&](RawG& r, int t) {
        const float* ps = ns + (size_t)sis[t] * 64 + 8 * g;
        const float* pd = ns + (size_t)dis[t] * 64 + 8 * g;
        r.v[0] = ld4v(ps);      r.v[1] = ld4v(ps + 4);
        r.v[2] = ld4v(ps + 32); r.v[3] = ld4v(ps + 36);
        r.v[4] = ld4v(pd);      r.v[5] = ld4v(pd + 4);
        r.v[6] = ld4v(pd + 32); r.v[7] = ld4v(pd + 36);
    };

    RawG r;
    load_gather(r, 0);

    #pragma unroll
    for (int t = 0; t < TPW; ++t) {
        const int ebase = (wtile0 + t) * 16;
        const int erow  = ebase + l15;

        // ---- streaming loads for THIS tile, issued up-front ----
        const float* pe = ef + (size_t)erow * 64;
        const float* pr = dd + (size_t)erow * 16;
        const f32x4 e0 = ld4v(pe + 8 * g), e1 = ld4v(pe + 8 * g + 4);
        const f32x4 e2 = ld4v(pe + 32 + 8 * g), e3 = ld4v(pe + 32 + 8 * g + 4);
        f32x4 r0 = {0.f,0.f,0.f,0.f}, r1 = {0.f,0.f,0.f,0.f};
        if (g < 2) { r0 = ld4v(pr + 8 * g); r1 = ld4v(pr + 8 * g + 4); }
        // residual quads in output layout (dims 16nn+4g..+3) -- L1/L2-hot re-read
        f32x4 efq[4];
        #pragma unroll
        for (int nn = 0; nn < 4; ++nn) efq[nn] = ld4v(pe + 16 * nn + 4 * g);

        // ---- pack B-operand fragments (x^T) ----
        bf16x8 a0 = pack8(r.v[0], r.v[1]);
        bf16x8 a1 = pack8(r.v[2], r.v[3]);
        bf16x8 a2f = pack8(r.v[4], r.v[5]);
        bf16x8 a3 = pack8(r.v[6], r.v[7]);
        bf16x8 a4 = pack8(e0, e1);
        bf16x8 a5 = pack8(e2, e3);
        bf16x8 a6 = pack8(r0, r1);

        // ---- prefetch next tile's gathers (WAR on r after pack) ----
        if (t < TPW - 1) load_gather(r, t + 1);

        // ---- layer 1: swapped operands (weights = A, activations = B) ----
        f32x4 acc[4];
        #pragma unroll
        for (int nn = 0; nn < 4; ++nn) acc[nn] = (f32x4){0.f, 0.f, 0.f, 0.f};
        #pragma unroll
        for (int nn = 0; nn < 4; ++nn) {
            acc[nn] = __builtin_amdgcn_mfma_f32_16x16x32_bf16(*reinterpret_cast<const bf16x8*>(&b1f[0][nn][lane][0]), a0, acc[nn], 0, 0, 0);
            acc[nn] = __builtin_amdgcn_mfma_f32_16x16x32_bf16(*reinterpret_cast<const bf16x8*>(&b1f[1][nn][lane][0]), a1, acc[nn], 0, 0, 0);
            acc[nn] = __builtin_amdgcn_mfma_f32_16x16x32_bf16(*reinterpret_cast<const bf16x8*>(&b1f[2][nn][lane][0]), a2f, acc[nn], 0, 0, 0);
            acc[nn] = __builtin_amdgcn_mfma_f32_16x16x32_bf16(*reinterpret_cast<const bf16x8*>(&b1f[3][nn][lane][0]), a3, acc[nn], 0, 0, 0);
            acc[nn] = __builtin_amdgcn_mfma_f32_16x16x32_bf16(*reinterpret_cast<const bf16x8*>(&b1f[4][nn][lane][0]), a4, acc[nn], 0, 0, 0);
            acc[nn] = __builtin_amdgcn_mfma_f32_16x16x32_bf16(*reinterpret_cast<const bf16x8*>(&b1f[5][nn][lane][0]), a5, acc[nn], 0, 0, 0);
            acc[nn] = __builtin_amdgcn_mfma_f32_16x16x32_bf16(*reinterpret_cast<const bf16x8*>(&b1f[6][nn][lane][0]), a6, acc[nn], 0, 0, 0);
        }

        // ---- silu + bias, pack layer-2 B operand from OWN registers ----
        // q_kk[j] = silu(h2[edge l15][delta(kk,g,j)])  with delta matching b2f's row permutation
        f32x4 sil[4];
        #pragma unroll
        for (int nn = 0; nn < 4; ++nn) {
            #pragma unroll
            for (int rr = 0; rr < 4; ++rr)
                sil[nn][rr] = silu_f(acc[nn][rr] + b1q[nn][rr]);
        }
        bf16x8 q0, q1;
        #pragma unroll
        for (int j = 0; j < 8; ++j) {
            q0[j] = (short)f2bf(sil[j >> 2][j & 3]);
            q1[j] = (short)f2bf(sil[2 + (j >> 2)][j & 3]);
        }

        // ---- layer 2 ----
        f32x4 acc2[4];
        #pragma unroll
        for (int nn = 0; nn < 4; ++nn) acc2[nn] = (f32x4){0.f, 0.f, 0.f, 0.f};
        #pragma unroll
        for (int nn = 0; nn < 4; ++nn) {
            acc2[nn] = __builtin_amdgcn_mfma_f32_16x16x32_bf16(*reinterpret_cast<const bf16x8*>(&b2f[0][nn][lane][0]), q0, acc2[nn], 0, 0, 0);
            acc2[nn] = __builtin_amdgcn_mfma_f32_16x16x32_bf16(*reinterpret_cast<const bf16x8*>(&b2f[1][nn][lane][0]), q1, acc2[nn], 0, 0, 0);
        }

        // ---- epilogue: silu + residual; LN over lane-local 16 dims + 2 shuffles ----
        f32x4 x[4];
        float s = 0.f;
        #pragma unroll
        for (int nn = 0; nn < 4; ++nn) {
            #pragma unroll
            for (int rr = 0; rr < 4; ++rr) {
                x[nn][rr] = silu_f(acc2[nn][rr] + b2q[nn][rr]) + efq[nn][rr];
                s += x[nn][rr];
            }
        }
        s += __shfl_xor(s, 16);
        s += __shfl_xor(s, 32);
        const float mean = s * (1.0f / 64.0f);

        float v = 0.f;
        #pragma unroll
        for (int nn = 0; nn < 4; ++nn) {
            #pragma unroll
            for (int rr = 0; rr < 4; ++rr) {
                const float dx = x[nn][rr] - mean;
                v += dx * dx;
            }
        }
        v += __shfl_xor(v, 16);
        v += __shfl_xor(v, 32);
        const float rsd = rsqrtf(v * (1.0f / 64.0f) + 1e-5f);

        float* obase = out + (size_t)erow * 64;
        #pragma unroll
        for (int nn = 0; nn < 4; ++nn) {
            const f32x4 lg = ld4v(lng + 16 * nn + 4 * g);   // L1-hot after first tile
            const f32x4 lb = ld4v(lnb + 16 * nn + 4 * g);
            f32x4 o;
            #pragma unroll
            for (int rr = 0; rr < 4; ++rr)
                o[rr] = (x[nn][rr] - mean) * rsd * lg[rr] + lb[rr];
            *reinterpret_cast<f32x4*>(obase + 16 * nn + 4 * g) = o;
        }
    }
}

// ---------------- Node kernel: 3 stacked GVPs (R8-proven) ----------------
template <int UOUT, bool SIG>
__device__ __forceinline__ void gvp_step(
    float* __restrict__ s, float* __restrict__ vv,
    const float* __restrict__ Wh, const float* __restrict__ Wu,
    const float* __restrict__ Ws, const float* __restrict__ bs,
    float (*cat)[NBLK], const int tid)
{
    #pragma unroll
    for (int j = 0; j < 64; ++j) cat[j][tid] = s[j];

    float vu[UOUT * 3];
    #pragma unroll
    for (int i = 0; i < UOUT * 3; ++i) vu[i] = 0.0f;

    for (int h = 0; h < V_CH; ++h) {
        float t0 = 0.0f, t1 = 0.0f, t2 = 0.0f;
        #pragma unroll
        for (int vi = 0; vi < V_CH; ++vi) {
            const float wv = Wh[vi * V_CH + h];
            t0 = fmaf(vv[vi * 3 + 0], wv, t0);
            t1 = fmaf(vv[vi * 3 + 1], wv, t1);
            t2 = fmaf(vv[vi * 3 + 2], wv, t2);
        }
        cat[64 + h][tid] = sqrtf(t0 * t0 + t1 * t1 + t2 * t2 + 1e-8f);
        #pragma unroll
        for (int u = 0; u < UOUT; ++u) {
            const float wu = Wu[h * UOUT + u];
            vu[u * 3 + 0] = fmaf(t0, wu, vu[u * 3 + 0]);
            vu[u * 3 + 1] = fmaf(t1, wu, vu[u * 3 + 1]);
            vu[u * 3 + 2] = fmaf(t2, wu, vu[u * 3 + 2]);
        }
    }

    float acc[64];
    #pragma unroll
    for (int j = 0; j < 64; ++j) acc[j] = bs[j];
    #pragma unroll 2
    for (int k = 0; k < 64 + V_CH; ++k) {
        const float hk = cat[k][tid];
        const float* w = Ws + (size_t)k * 64;
        #pragma unroll
        for (int j = 0; j < 64; ++j) acc[j] = fmaf(hk, w[j], acc[j]);
    }
    #pragma unroll
    for (int j = 0; j < 64; ++j) s[j] = silu_f(acc[j]);

    #pragma unroll
    for (int u = 0; u < UOUT; ++u) {
        const float a = vu[u * 3 + 0];
        const float b = vu[u * 3 + 1];
        const float c = vu[u * 3 + 2];
        const float vn = sqrtf(a * a + b * b + c * c + 1e-8f);
        const float gt = SIG ? (1.0f / (1.0f + __expf(-vn))) : vn;
        vv[u * 3 + 0] = gt * a;
        vv[u * 3 + 1] = gt * b;
        vv[u * 3 + 2] = gt * c;
    }
}

__global__ __launch_bounds__(NBLK, 2) void node_kernel(
    const float* __restrict__ ns, const float* __restrict__ pos,
    const float* __restrict__ vec,
    const float* __restrict__ Wh0, const float* __restrict__ Wu0,
    const float* __restrict__ Ws0, const float* __restrict__ bs0,
    const float* __restrict__ Wh1, const float* __restrict__ Wu1,
    const float* __restrict__ Ws1, const float* __restrict__ bs1,
    const float* __restrict__ Wh2, const float* __restrict__ Wu2,
    const float* __restrict__ Ws2, const float* __restrict__ bs2,
    float* __restrict__ outpos)
{
    __shared__ float cat[64 + V_CH][NBLK];
    const int tid = threadIdx.x;
    const int n = blockIdx.x * NBLK + tid;
    const bool active = (n < N_NODES);
    const int nc = active ? n : 0;

    float s[64];
    {
        const float* p = ns + (size_t)nc * S_DIM;
        #pragma unroll
        for (int i = 0; i < 16; ++i) {
            float4 v4 = *reinterpret_cast<const float4*>(p + 4 * i);
            s[4 * i] = v4.x; s[4 * i + 1] = v4.y; s[4 * i + 2] = v4.z; s[4 * i + 3] = v4.w;
        }
    }
    float vv[48];
    {
        const float* p = vec + (size_t)nc * (V_CH * 3);
        #pragma unroll
        for (int i = 0; i < 12; ++i) {
            float4 v4 = *reinterpret_cast<const float4*>(p + 4 * i);
            vv[4 * i] = v4.x; vv[4 * i + 1] = v4.y; vv[4 * i + 2] = v4.z; vv[4 * i + 3] = v4.w;
        }
    }

    gvp_step<V_CH, true>(s, vv, Wh0, Wu0, Ws0, bs0, cat, tid);
    gvp_step<V_CH, true>(s, vv, Wh1, Wu1, Ws1, bs1, cat, tid);
    gvp_step<1, false>(s, vv, Wh2, Wu2, Ws2, bs2, cat, tid);

    if (active) {
        outpos[(size_t)n * 3 + 0] = pos[(size_t)n * 3 + 0] + vv[0];
        outpos[(size_t)n * 3 + 1] = pos[(size_t)n * 3 + 1] + vv[1];
        outpos[(size_t)n * 3 + 2] = pos[(size_t)n * 3 + 2] + vv[2];
    }
}

extern "C" void kernel_launch(void* const* d_in, const int* in_sizes, int n_in,
                              void* d_out, int out_size, void* d_ws, size_t ws_size,
                              hipStream_t stream) {
    const float* ns  = (const float*)d_in[0];
    const float* pos = (const float*)d_in[1];
    const float* vec = (const float*)d_in[2];
    const float* ef  = (const float*)d_in[3];
    const float* dd  = (const float*)d_in[4];
    const int*   src = (const int*)d_in[5];
    const int*   dst = (const int*)d_in[6];
    const float* W1  = (const float*)d_in[7];
    const float* b1  = (const float*)d_in[8];
    const float* W2  = (const float*)d_in[9];
    const float* b2  = (const float*)d_in[10];
    const float* lng = (const float*)d_in[11];
    const float* lnb = (const float*)d_in[12];
    const float* Wh0 = (const float*)d_in[13];
    const float* Wu0 = (const float*)d_in[14];
    const float* Ws0 = (const float*)d_in[15];
    const float* bs0 = (const float*)d_in[16];
    const float* Wh1 = (const float*)d_in[17];
    const float* Wu1 = (const float*)d_in[18];
    const float* Ws1 = (const float*)d_in[19];
    const float* bs1 = (const float*)d_in[20];
    const float* Wh2 = (const float*)d_in[21];
    const float* Wu2 = (const float*)d_in[22];
    const float* Ws2 = (const float*)d_in[23];
    const float* bs2 = (const float*)d_in[24];

    float* out     = (float*)d_out;
    float* out_pos = out + (size_t)N_EDGES * F_DIM;

    edge_kernel<<<EDGE_GRID, 256, 0, stream>>>(
        ns, ef, dd, src, dst, W1, b1, W2, b2, lng, lnb, out);
    node_kernel<<<(N_NODES + NBLK - 1) / NBLK, NBLK, 0, stream>>>(
        ns, pos, vec, Wh0, Wu0, Ws0, bs0, Wh1, Wu1, Ws1, bs1, Wh2, Wu2, Ws2, bs2, out_pos);
}